// Round 1
// baseline (2312.266 us; speedup 1.0000x reference)
//
#include <hip/hip_runtime.h>
#include <math.h>

#define T_LEN 2048
#define B_SZ 2
#define EMB 1024
#define HEADS 16
#define HD 64
#define BH (B_SZ*HEADS)       // 32
#define R_ROWS (T_LEN*B_SZ)   // 4096
#define LD 68                 // padded LDS leading dim (float4-aligned, conflict-friendly)

// ---------------- projection GEMM: out = X @ W^T + bias, optional scale ------
// X: [R_ROWS][EMB] row-major (row r = t*B + b), W: [EMB][EMB] row-major (nn.Linear)
// headMajor=1: write to [b*H+h][t][d]; headMajor=0: write [r][o]
__global__ __launch_bounds__(256)
void proj_kernel(const float* __restrict__ X, const float* __restrict__ W,
                 const float* __restrict__ bias, float* __restrict__ out,
                 float scale, int headMajor)
{
    __shared__ float As[16][65];
    __shared__ float Bs[16][65];
    const int m0 = blockIdx.x * 64;
    const int n0 = blockIdx.y * 64;
    const int tid = threadIdx.x;
    const int tx = tid & 15, ty = tid >> 4;
    const int lr = tid >> 2;            // 0..63
    const int lc = (tid & 3) << 2;      // 0,4,8,12
    float acc[4][4] = {};
    for (int k0 = 0; k0 < EMB; k0 += 16) {
        float4 a = *(const float4*)(X + (size_t)(m0 + lr) * EMB + k0 + lc);
        float4 w = *(const float4*)(W + (size_t)(n0 + lr) * EMB + k0 + lc);
        As[lc+0][lr]=a.x; As[lc+1][lr]=a.y; As[lc+2][lr]=a.z; As[lc+3][lr]=a.w;
        Bs[lc+0][lr]=w.x; Bs[lc+1][lr]=w.y; Bs[lc+2][lr]=w.z; Bs[lc+3][lr]=w.w;
        __syncthreads();
#pragma unroll
        for (int k = 0; k < 16; ++k) {
            float ar[4], br[4];
#pragma unroll
            for (int i = 0; i < 4; ++i) ar[i] = As[k][ty*4+i];
#pragma unroll
            for (int j = 0; j < 4; ++j) br[j] = Bs[k][tx*4+j];
#pragma unroll
            for (int i = 0; i < 4; ++i)
#pragma unroll
                for (int j = 0; j < 4; ++j) acc[i][j] += ar[i]*br[j];
        }
        __syncthreads();
    }
    if (headMajor) {
        const int h = n0 >> 6;   // TILE_N == HD, so one n-tile == one head
#pragma unroll
        for (int i = 0; i < 4; ++i) {
            int r = m0 + ty*4 + i;
            int t = r >> 1, b = r & 1;
            float4 v;
            v.x = (acc[i][0] + bias[n0 + tx*4 + 0]) * scale;
            v.y = (acc[i][1] + bias[n0 + tx*4 + 1]) * scale;
            v.z = (acc[i][2] + bias[n0 + tx*4 + 2]) * scale;
            v.w = (acc[i][3] + bias[n0 + tx*4 + 3]) * scale;
            *(float4*)(out + ((size_t)(b*HEADS + h)*T_LEN + t)*HD + tx*4) = v;
        }
    } else {
#pragma unroll
        for (int i = 0; i < 4; ++i) {
            int r = m0 + ty*4 + i;
            float4 v;
            v.x = (acc[i][0] + bias[n0 + tx*4 + 0]) * scale;
            v.y = (acc[i][1] + bias[n0 + tx*4 + 1]) * scale;
            v.z = (acc[i][2] + bias[n0 + tx*4 + 2]) * scale;
            v.w = (acc[i][3] + bias[n0 + tx*4 + 3]) * scale;
            *(float4*)(out + (size_t)r*EMB + n0 + tx*4) = v;
        }
    }
}

// ---------------- flash attention per (bh, 64-row q tile) --------------------
__global__ __launch_bounds__(256)
void flash_kernel(const float* __restrict__ qh, const float* __restrict__ kh,
                  const float* __restrict__ vh, float* __restrict__ attn,
                  float* __restrict__ mbuf, float* __restrict__ lbuf)
{
    __shared__ float Qs[64][LD];
    __shared__ float Kt[64][LD];   // transposed: Kt[d][s]
    __shared__ float Vs[64][LD];
    __shared__ float Ps[64][LD];
    const int bh = blockIdx.y;
    const int t0 = blockIdx.x * 64;
    const int tid = threadIdx.x;
    const int tx = tid & 15, ty = tid >> 4;
    const float* Qg = qh + ((size_t)bh*T_LEN + t0)*HD;
#pragma unroll
    for (int i = 0; i < 4; ++i) {
        int f4 = i*256 + tid;
        int row = f4 >> 4, c4 = (f4 & 15) << 2;
        *(float4*)&Qs[row][c4] = *(const float4*)(Qg + row*HD + c4);
    }
    float m_i[4], l_i[4], o[4][4];
#pragma unroll
    for (int i = 0; i < 4; ++i) {
        m_i[i] = -INFINITY; l_i[i] = 0.f;
#pragma unroll
        for (int j = 0; j < 4; ++j) o[i][j] = 0.f;
    }
    for (int s0 = 0; s0 < T_LEN; s0 += 64) {
        const float* Kg = kh + ((size_t)bh*T_LEN + s0)*HD;
        const float* Vg = vh + ((size_t)bh*T_LEN + s0)*HD;
        __syncthreads();   // previous iteration done with Kt/Vs (and Qs stores visible)
#pragma unroll
        for (int i = 0; i < 4; ++i) {
            int f4 = i*256 + tid;
            int row = f4 >> 4, c4 = (f4 & 15) << 2;
            float4 kv = *(const float4*)(Kg + row*HD + c4);
            Kt[c4+0][row]=kv.x; Kt[c4+1][row]=kv.y; Kt[c4+2][row]=kv.z; Kt[c4+3][row]=kv.w;
            *(float4*)&Vs[row][c4] = *(const float4*)(Vg + row*HD + c4);
        }
        __syncthreads();
        float sc[4][4] = {};
#pragma unroll
        for (int d4 = 0; d4 < HD; d4 += 4) {
            float4 q4[4], kt[4];
#pragma unroll
            for (int i = 0; i < 4; ++i) q4[i] = *(const float4*)&Qs[ty*4+i][d4];
#pragma unroll
            for (int dd = 0; dd < 4; ++dd) kt[dd] = *(const float4*)&Kt[d4+dd][tx*4];
#pragma unroll
            for (int i = 0; i < 4; ++i) {
                sc[i][0] += q4[i].x*kt[0].x + q4[i].y*kt[1].x + q4[i].z*kt[2].x + q4[i].w*kt[3].x;
                sc[i][1] += q4[i].x*kt[0].y + q4[i].y*kt[1].y + q4[i].z*kt[2].y + q4[i].w*kt[3].y;
                sc[i][2] += q4[i].x*kt[0].z + q4[i].y*kt[1].z + q4[i].z*kt[2].z + q4[i].w*kt[3].z;
                sc[i][3] += q4[i].x*kt[0].w + q4[i].y*kt[1].w + q4[i].z*kt[2].w + q4[i].w*kt[3].w;
            }
        }
        // online softmax (row groups of 16 lanes share ty)
#pragma unroll
        for (int i = 0; i < 4; ++i) {
            float mx = fmaxf(fmaxf(sc[i][0],sc[i][1]), fmaxf(sc[i][2],sc[i][3]));
#pragma unroll
            for (int off = 8; off >= 1; off >>= 1) mx = fmaxf(mx, __shfl_xor(mx, off, 16));
            float mnew = fmaxf(m_i[i], mx);
            float alpha = expf(m_i[i] - mnew);
            m_i[i] = mnew;
            float p0 = expf(sc[i][0]-mnew), p1 = expf(sc[i][1]-mnew);
            float p2 = expf(sc[i][2]-mnew), p3 = expf(sc[i][3]-mnew);
            float rs = p0+p1+p2+p3;
#pragma unroll
            for (int off = 8; off >= 1; off >>= 1) rs += __shfl_xor(rs, off, 16);
            l_i[i] = l_i[i]*alpha + rs;
#pragma unroll
            for (int j = 0; j < 4; ++j) o[i][j] *= alpha;
            *(float4*)&Ps[ty*4+i][tx*4] = make_float4(p0,p1,p2,p3);
        }
        __syncthreads();
#pragma unroll
        for (int c4 = 0; c4 < 64; c4 += 4) {
            float4 p4[4], vv[4];
#pragma unroll
            for (int i = 0; i < 4; ++i) p4[i] = *(const float4*)&Ps[ty*4+i][c4];
#pragma unroll
            for (int cc = 0; cc < 4; ++cc) vv[cc] = *(const float4*)&Vs[c4+cc][tx*4];
#pragma unroll
            for (int i = 0; i < 4; ++i) {
                o[i][0] += p4[i].x*vv[0].x + p4[i].y*vv[1].x + p4[i].z*vv[2].x + p4[i].w*vv[3].x;
                o[i][1] += p4[i].x*vv[0].y + p4[i].y*vv[1].y + p4[i].z*vv[2].y + p4[i].w*vv[3].y;
                o[i][2] += p4[i].x*vv[0].z + p4[i].y*vv[1].z + p4[i].z*vv[2].z + p4[i].w*vv[3].z;
                o[i][3] += p4[i].x*vv[0].w + p4[i].y*vv[1].w + p4[i].z*vv[2].w + p4[i].w*vv[3].w;
            }
        }
    }
    const int b = bh >> 4, h = bh & 15;
#pragma unroll
    for (int i = 0; i < 4; ++i) {
        int t = t0 + ty*4 + i;
        if (tx == 0) { mbuf[bh*T_LEN + t] = m_i[i]; lbuf[bh*T_LEN + t] = l_i[i]; }
        float inv = 1.0f / l_i[i];
        float4 v = make_float4(o[i][0]*inv, o[i][1]*inv, o[i][2]*inv, o[i][3]*inv);
        *(float4*)(attn + ((size_t)t*B_SZ + b)*EMB + h*HD + tx*4) = v;
    }
}

// ---------------- avg weights: recompute scores, apply saved (m,l) ----------
__global__ __launch_bounds__(256)
void avg_kernel(const float* __restrict__ qh, const float* __restrict__ kh,
                const float* __restrict__ mbuf, const float* __restrict__ lbuf,
                float* __restrict__ avg)
{
    __shared__ float Qs[64][LD];
    __shared__ float Kt[64][LD];
    const int s0 = blockIdx.x * 64;
    const int t0 = blockIdx.y * 64;
    const int b  = blockIdx.z;
    const int tid = threadIdx.x;
    const int tx = tid & 15, ty = tid >> 4;
    float acc[4][4] = {};
    for (int h = 0; h < HEADS; ++h) {
        int bh = b*HEADS + h;
        const float* Qg = qh + ((size_t)bh*T_LEN + t0)*HD;
        const float* Kg = kh + ((size_t)bh*T_LEN + s0)*HD;
        __syncthreads();
#pragma unroll
        for (int i = 0; i < 4; ++i) {
            int f4 = i*256 + tid;
            int row = f4 >> 4, c4 = (f4 & 15) << 2;
            *(float4*)&Qs[row][c4] = *(const float4*)(Qg + row*HD + c4);
            float4 kv = *(const float4*)(Kg + row*HD + c4);
            Kt[c4+0][row]=kv.x; Kt[c4+1][row]=kv.y; Kt[c4+2][row]=kv.z; Kt[c4+3][row]=kv.w;
        }
        __syncthreads();
        float sc[4][4] = {};
#pragma unroll
        for (int d4 = 0; d4 < HD; d4 += 4) {
            float4 q4[4], kt[4];
#pragma unroll
            for (int i = 0; i < 4; ++i) q4[i] = *(const float4*)&Qs[ty*4+i][d4];
#pragma unroll
            for (int dd = 0; dd < 4; ++dd) kt[dd] = *(const float4*)&Kt[d4+dd][tx*4];
#pragma unroll
            for (int i = 0; i < 4; ++i) {
                sc[i][0] += q4[i].x*kt[0].x + q4[i].y*kt[1].x + q4[i].z*kt[2].x + q4[i].w*kt[3].x;
                sc[i][1] += q4[i].x*kt[0].y + q4[i].y*kt[1].y + q4[i].z*kt[2].y + q4[i].w*kt[3].y;
                sc[i][2] += q4[i].x*kt[0].z + q4[i].y*kt[1].z + q4[i].z*kt[2].z + q4[i].w*kt[3].z;
                sc[i][3] += q4[i].x*kt[0].w + q4[i].y*kt[1].w + q4[i].z*kt[2].w + q4[i].w*kt[3].w;
            }
        }
        float mrow[4], linv[4];
#pragma unroll
        for (int i = 0; i < 4; ++i) {
            mrow[i] = mbuf[bh*T_LEN + t0 + ty*4 + i];
            linv[i] = 1.0f / lbuf[bh*T_LEN + t0 + ty*4 + i];
        }
#pragma unroll
        for (int i = 0; i < 4; ++i)
#pragma unroll
            for (int j = 0; j < 4; ++j)
                acc[i][j] += expf(sc[i][j] - mrow[i]) * linv[i];
    }
    const float s = 1.0f / HEADS;
#pragma unroll
    for (int i = 0; i < 4; ++i) {
        int t = t0 + ty*4 + i;
        float4 v = make_float4(acc[i][0]*s, acc[i][1]*s, acc[i][2]*s, acc[i][3]*s);
        *(float4*)(avg + ((size_t)b*T_LEN + t)*T_LEN + s0 + tx*4) = v;
    }
}

extern "C" void kernel_launch(void* const* d_in, const int* in_sizes, int n_in,
                              void* d_out, int out_size, void* d_ws, size_t ws_size,
                              hipStream_t stream)
{
    const float* query = (const float*)d_in[0];
    const float* key   = (const float*)d_in[1];
    const float* value = (const float*)d_in[2];
    const float* Wq = (const float*)d_in[3];
    const float* bq = (const float*)d_in[4];
    const float* Wk = (const float*)d_in[5];
    const float* bk = (const float*)d_in[6];
    const float* Wv = (const float*)d_in[7];
    const float* bv = (const float*)d_in[8];
    const float* Wo = (const float*)d_in[9];
    const float* bo = (const float*)d_in[10];

    float* out = (float*)d_out;                 // [T,B,E] = 4,194,304 floats
    float* avg = out + (size_t)R_ROWS*EMB;      // [B,T,S] = 8,388,608 floats

    float* ws   = (float*)d_ws;
    float* qh   = ws;                                   // [BH][T][HD]
    float* khp  = qh  + (size_t)BH*T_LEN*HD;
    float* vhp  = khp + (size_t)BH*T_LEN*HD;
    float* mbuf = vhp + (size_t)BH*T_LEN*HD;            // [BH][T]
    float* lbuf = mbuf + (size_t)BH*T_LEN;
    float* attn = lbuf + (size_t)BH*T_LEN;              // [T,B,E]

    const float scale = 0.125f;  // HEAD_DIM^-0.5

    dim3 gGemm(R_ROWS/64, EMB/64);
    proj_kernel<<<gGemm, 256, 0, stream>>>(query, Wq, bq, qh,  scale, 1);
    proj_kernel<<<gGemm, 256, 0, stream>>>(key,   Wk, bk, khp, 1.0f,  1);
    proj_kernel<<<gGemm, 256, 0, stream>>>(value, Wv, bv, vhp, 1.0f,  1);
    flash_kernel<<<dim3(T_LEN/64, BH), 256, 0, stream>>>(qh, khp, vhp, attn, mbuf, lbuf);
    proj_kernel<<<gGemm, 256, 0, stream>>>(attn, Wo, bo, out, 1.0f, 0);
    avg_kernel<<<dim3(T_LEN/64, T_LEN/64, B_SZ), 256, 0, stream>>>(qh, khp, mbuf, lbuf, avg);
}

// Round 2
// 1082.420 us; speedup vs baseline: 2.1362x; 2.1362x over previous
//
#include <hip/hip_runtime.h>
#include <math.h>

#define T_LEN 2048
#define B_SZ 2
#define EMB 1024
#define HEADS 16
#define HD 64
#define BH (B_SZ*HEADS)       // 32
#define R_ROWS (T_LEN*B_SZ)   // 4096

typedef __attribute__((ext_vector_type(8))) short bf16x8;
typedef __attribute__((ext_vector_type(4))) short bf16x4;
typedef __attribute__((ext_vector_type(4))) float f32x4;

#define MFMA32(a,b,c) __builtin_amdgcn_mfma_f32_16x16x32_bf16(a,b,c,0,0,0)
#if __has_builtin(__builtin_amdgcn_mfma_f32_16x16x16_bf16)
#define MFMA16(a,b,c) __builtin_amdgcn_mfma_f32_16x16x16_bf16(a,b,c,0,0,0)
#else
#define MFMA16(a,b,c) __builtin_amdgcn_mfma_f32_16x16x16bf16_1k(a,b,c,0,0,0)
#endif

__device__ __forceinline__ unsigned short f2bf(float f) {
    union { float f; unsigned int u; } v; v.f = f;
    unsigned int r = v.u + 0x7fffu + ((v.u >> 16) & 1u);
    return (unsigned short)(r >> 16);
}
__device__ __forceinline__ float bf2f(unsigned short h) {
    union { unsigned int u; float f; } v; v.u = ((unsigned int)h) << 16;
    return v.f;
}
__device__ __forceinline__ ushort4 hi4(float4 x) {
    ushort4 u; u.x = f2bf(x.x); u.y = f2bf(x.y); u.z = f2bf(x.z); u.w = f2bf(x.w); return u;
}
__device__ __forceinline__ ushort4 lo4(float4 x, ushort4 h) {
    ushort4 u;
    u.x = f2bf(x.x - bf2f(h.x));
    u.y = f2bf(x.y - bf2f(h.y));
    u.z = f2bf(x.z - bf2f(h.z));
    u.w = f2bf(x.w - bf2f(h.w));
    return u;
}

// ---------------- projection GEMM: out = X @ W^T + bias, optional scale ------
// mode 0: out[r][o] row-major; mode 1: head-major [bh][t][d]; mode 2: transposed
// head-major [bh][d][t] (for V, so flash PV B-frags are contiguous in LDS).
__global__ __launch_bounds__(256)
void proj_kernel(const float* __restrict__ X, const float* __restrict__ W,
                 const float* __restrict__ bias, float* __restrict__ out,
                 float scale, int mode)
{
    __shared__ float As[16][65];
    __shared__ float Bs[16][65];
    const int m0 = blockIdx.x * 64;
    const int n0 = blockIdx.y * 64;
    const int tid = threadIdx.x;
    const int tx = tid & 15, ty = tid >> 4;
    const int lr = tid >> 2;
    const int lc = (tid & 3) << 2;
    float acc[4][4] = {};
    for (int k0 = 0; k0 < EMB; k0 += 16) {
        float4 a = *(const float4*)(X + (size_t)(m0 + lr) * EMB + k0 + lc);
        float4 w = *(const float4*)(W + (size_t)(n0 + lr) * EMB + k0 + lc);
        As[lc+0][lr]=a.x; As[lc+1][lr]=a.y; As[lc+2][lr]=a.z; As[lc+3][lr]=a.w;
        Bs[lc+0][lr]=w.x; Bs[lc+1][lr]=w.y; Bs[lc+2][lr]=w.z; Bs[lc+3][lr]=w.w;
        __syncthreads();
#pragma unroll
        for (int k = 0; k < 16; ++k) {
            float ar[4], br[4];
#pragma unroll
            for (int i = 0; i < 4; ++i) ar[i] = As[k][ty*4+i];
#pragma unroll
            for (int j = 0; j < 4; ++j) br[j] = Bs[k][tx*4+j];
#pragma unroll
            for (int i = 0; i < 4; ++i)
#pragma unroll
                for (int j = 0; j < 4; ++j) acc[i][j] += ar[i]*br[j];
        }
        __syncthreads();
    }
    if (mode == 1) {
        const int h = n0 >> 6;
#pragma unroll
        for (int i = 0; i < 4; ++i) {
            int r = m0 + ty*4 + i;
            int t = r >> 1, b = r & 1;
            float4 v;
            v.x = (acc[i][0] + bias[n0 + tx*4 + 0]) * scale;
            v.y = (acc[i][1] + bias[n0 + tx*4 + 1]) * scale;
            v.z = (acc[i][2] + bias[n0 + tx*4 + 2]) * scale;
            v.w = (acc[i][3] + bias[n0 + tx*4 + 3]) * scale;
            *(float4*)(out + ((size_t)(b*HEADS + h)*T_LEN + t)*HD + tx*4) = v;
        }
    } else if (mode == 0) {
#pragma unroll
        for (int i = 0; i < 4; ++i) {
            int r = m0 + ty*4 + i;
            float4 v;
            v.x = (acc[i][0] + bias[n0 + tx*4 + 0]) * scale;
            v.y = (acc[i][1] + bias[n0 + tx*4 + 1]) * scale;
            v.z = (acc[i][2] + bias[n0 + tx*4 + 2]) * scale;
            v.w = (acc[i][3] + bias[n0 + tx*4 + 3]) * scale;
            *(float4*)(out + (size_t)r*EMB + n0 + tx*4) = v;
        }
    } else {  // mode 2: transposed head-major out[(bh*HD + d)*T + t]
        __shared__ float Ts[64][65];
        const int h = n0 >> 6;
#pragma unroll
        for (int i = 0; i < 4; ++i)
#pragma unroll
            for (int j = 0; j < 4; ++j)
                Ts[ty*4+i][tx*4+j] = (acc[i][j] + bias[n0 + tx*4 + j]) * scale;
        __syncthreads();
        const int t0p = m0 >> 1;
#pragma unroll
        for (int i = 0; i < 4; ++i) {
            int f4 = i*256 + tid;
            int d = f4 >> 4;
            int u = f4 & 15;
            int bb = u >> 3;
            int t4 = (u & 7) << 2;
            float4 o;
            o.x = Ts[(t4+0)*2 + bb][d];
            o.y = Ts[(t4+1)*2 + bb][d];
            o.z = Ts[(t4+2)*2 + bb][d];
            o.w = Ts[(t4+3)*2 + bb][d];
            *(float4*)(out + ((size_t)(bb*HEADS + h)*HD + d)*T_LEN + t0p + t4) = o;
        }
    }
}

// ---------------- MFMA flash attention ---------------------------------------
// Block: 256 thr (4 waves), covers 128 t per (bh). Wave w owns t-cols
// w*32..w*32+31 (2 n-tiles). Scores computed TRANSPOSED (S^T = K·Q^T) so the
// C-frag (row=s=4q+r, col=t=lane&15) is directly the A-frag of the 16x16x16
// PV MFMA (A[m=lane&15][k=4q+i]) — P never goes through LDS.
// QK^T is hi/lo-compensated bf16 (near-fp32 scores -> m,l accurate for avg).
__global__ __launch_bounds__(256)
void flash_kernel(const float* __restrict__ qh, const float* __restrict__ kh,
                  const float* __restrict__ vt, float* __restrict__ attn,
                  float* __restrict__ mbuf, float* __restrict__ lbuf)
{
    __shared__ __align__(16) unsigned short Khi[64][72];
    __shared__ __align__(16) unsigned short Klo[64][72];
    __shared__ __align__(16) unsigned short Vts[64][72];
    const int tid = threadIdx.x;
    const int w  = tid >> 6;
    const int ln = tid & 63;
    const int lm = ln & 15;
    const int lq = ln >> 4;
    const int bh = blockIdx.y;
    const int t0 = blockIdx.x * 128;
    const int b = bh >> 4, h = bh & 15;
    const float* qg = qh + ((size_t)bh*T_LEN + t0)*HD;
    const float* kg = kh + (size_t)bh*T_LEN*HD;
    const float* vg = vt + (size_t)bh*HD*T_LEN;

    // preload Q B-frags (hi & lo) via two staging passes through Khi/Klo
    bf16x8 qfhi[2][2], qflo[2][2];
#pragma unroll
    for (int pass = 0; pass < 2; ++pass) {
#pragma unroll
        for (int i = 0; i < 8; ++i) {
            int f4 = i*256 + tid;
            int r = f4 >> 4, c4 = (f4 & 15) << 2;
            float4 x = *(const float4*)(qg + r*HD + c4);
            ushort4 uh = hi4(x);
            ushort4 u = pass ? lo4(x, uh) : uh;
            unsigned short* dst = (r < 64) ? &Khi[r][c4] : &Klo[r-64][c4];
            *(ushort4*)dst = u;
        }
        __syncthreads();
#pragma unroll
        for (int nt = 0; nt < 2; ++nt) {
            int tr = w*32 + nt*16 + lm;
            const unsigned short* base = (tr < 64) ? &Khi[tr][0] : &Klo[tr-64][0];
#pragma unroll
            for (int f = 0; f < 2; ++f) {
                bf16x8 v = *(const bf16x8*)(base + f*32 + lq*8);
                if (pass) qflo[nt][f] = v; else qfhi[nt][f] = v;
            }
        }
        __syncthreads();
    }

    f32x4 O[2][4];
    float m_t[2], l_t[2];
#pragma unroll
    for (int nt = 0; nt < 2; ++nt) {
        m_t[nt] = -INFINITY; l_t[nt] = 0.f;
#pragma unroll
        for (int dt = 0; dt < 4; ++dt) O[nt][dt] = (f32x4){0.f,0.f,0.f,0.f};
    }

    for (int s0 = 0; s0 < T_LEN; s0 += 64) {
        __syncthreads();
#pragma unroll
        for (int i = 0; i < 4; ++i) {
            int f4 = i*256 + tid;
            int r = f4 >> 4, c4 = (f4 & 15) << 2;
            float4 kx = *(const float4*)(kg + (size_t)(s0 + r)*HD + c4);
            ushort4 khh = hi4(kx);
            *(ushort4*)&Khi[r][c4] = khh;
            *(ushort4*)&Klo[r][c4] = lo4(kx, khh);
            float4 vx = *(const float4*)(vg + (size_t)r*T_LEN + s0 + c4);
            *(ushort4*)&Vts[r][c4] = hi4(vx);
        }
        __syncthreads();

        f32x4 S[2][4];
#pragma unroll
        for (int ms = 0; ms < 4; ++ms) {
            const int krow = ms*16 + lm;
            bf16x8 ah0 = *(const bf16x8*)&Khi[krow][lq*8];
            bf16x8 ah1 = *(const bf16x8*)&Khi[krow][lq*8+32];
            bf16x8 al0 = *(const bf16x8*)&Klo[krow][lq*8];
            bf16x8 al1 = *(const bf16x8*)&Klo[krow][lq*8+32];
#pragma unroll
            for (int nt = 0; nt < 2; ++nt) {
                f32x4 s4 = {0.f,0.f,0.f,0.f};
                s4 = MFMA32(al0, qfhi[nt][0], s4);
                s4 = MFMA32(al1, qfhi[nt][1], s4);
                s4 = MFMA32(ah0, qflo[nt][0], s4);
                s4 = MFMA32(ah1, qflo[nt][1], s4);
                s4 = MFMA32(ah0, qfhi[nt][0], s4);
                s4 = MFMA32(ah1, qfhi[nt][1], s4);
                S[nt][ms] = s4;
            }
        }

        // online softmax over s (rows of S^T): reduce regs + shfl_xor 16,32
        bf16x4 P[2][4];
        float alpha[2];
#pragma unroll
        for (int nt = 0; nt < 2; ++nt) {
            float mx = -INFINITY;
#pragma unroll
            for (int ms = 0; ms < 4; ++ms)
#pragma unroll
                for (int r = 0; r < 4; ++r) mx = fmaxf(mx, S[nt][ms][r]);
            mx = fmaxf(mx, __shfl_xor(mx, 16));
            mx = fmaxf(mx, __shfl_xor(mx, 32));
            float mn = fmaxf(m_t[nt], mx);
            alpha[nt] = __expf(m_t[nt] - mn);
            m_t[nt] = mn;
            float rs = 0.f;
#pragma unroll
            for (int ms = 0; ms < 4; ++ms) {
                float p0 = __expf(S[nt][ms][0]-mn);
                float p1 = __expf(S[nt][ms][1]-mn);
                float p2 = __expf(S[nt][ms][2]-mn);
                float p3 = __expf(S[nt][ms][3]-mn);
                rs += (p0+p1)+(p2+p3);
                bf16x4 pk;
                pk[0] = (short)f2bf(p0); pk[1] = (short)f2bf(p1);
                pk[2] = (short)f2bf(p2); pk[3] = (short)f2bf(p3);
                P[nt][ms] = pk;
            }
            rs += __shfl_xor(rs, 16);
            rs += __shfl_xor(rs, 32);
            l_t[nt] = l_t[nt]*alpha[nt] + rs;
        }
        // rescale O (O rows are t=4*lq+r; alpha lives at lane t=lane&15)
#pragma unroll
        for (int nt = 0; nt < 2; ++nt) {
            f32x4 av;
#pragma unroll
            for (int r = 0; r < 4; ++r) av[r] = __shfl(alpha[nt], lq*4 + r);
#pragma unroll
            for (int dt = 0; dt < 4; ++dt) O[nt][dt] *= av;
        }
        // PV: A = P (in regs), B = V from transposed LDS (contiguous b64)
#pragma unroll
        for (int dt = 0; dt < 4; ++dt) {
#pragma unroll
            for (int ms = 0; ms < 4; ++ms) {
                bf16x4 vf = *(const bf16x4*)&Vts[dt*16 + lm][ms*16 + lq*4];
#pragma unroll
                for (int nt = 0; nt < 2; ++nt)
                    O[nt][dt] = MFMA16(P[nt][ms], vf, O[nt][dt]);
            }
        }
    }

#pragma unroll
    for (int nt = 0; nt < 2; ++nt) {
        float inv = 1.0f / l_t[nt];
        f32x4 iv;
#pragma unroll
        for (int r = 0; r < 4; ++r) iv[r] = __shfl(inv, lq*4 + r);
        int tbase = t0 + w*32 + nt*16;
        if (lq == 0) {
            mbuf[(size_t)bh*T_LEN + tbase + lm] = m_t[nt];
            lbuf[(size_t)bh*T_LEN + tbase + lm] = l_t[nt];
        }
#pragma unroll
        for (int dt = 0; dt < 4; ++dt)
#pragma unroll
            for (int r = 0; r < 4; ++r) {
                int t = tbase + lq*4 + r;
                attn[((size_t)t*B_SZ + b)*EMB + h*HD + dt*16 + lm] = O[nt][dt][r] * iv[r];
            }
    }
}

// ---------------- avg weights: MFMA recompute of S^T, apply saved (m,l) ------
// Block: (b, t0 128, s0 128); loop h, accumulate exp(s-m)/l over heads.
__global__ __launch_bounds__(256)
void avg_kernel(const float* __restrict__ qh, const float* __restrict__ kh,
                const float* __restrict__ mbuf, const float* __restrict__ lbuf,
                float* __restrict__ avg)
{
    __shared__ __align__(16) unsigned short Khi[128][72];
    __shared__ __align__(16) unsigned short Klo[128][72];
    const int tid = threadIdx.x;
    const int w = tid >> 6, ln = tid & 63, lm = ln & 15, lq = ln >> 4;
    const int s0 = blockIdx.x * 128;
    const int t0 = blockIdx.y * 128;
    const int b  = blockIdx.z;
    f32x4 acc[2][8];
#pragma unroll
    for (int nt = 0; nt < 2; ++nt)
#pragma unroll
        for (int ms = 0; ms < 8; ++ms) acc[nt][ms] = (f32x4){0.f,0.f,0.f,0.f};

    for (int h = 0; h < HEADS; ++h) {
        const int bh = b*HEADS + h;
        __syncthreads();
#pragma unroll
        for (int i = 0; i < 8; ++i) {
            int f4 = i*256 + tid;
            int r = f4 >> 4, c4 = (f4 & 15) << 2;
            float4 kx = *(const float4*)(kh + ((size_t)bh*T_LEN + s0 + r)*HD + c4);
            ushort4 hh = hi4(kx);
            *(ushort4*)&Khi[r][c4] = hh;
            *(ushort4*)&Klo[r][c4] = lo4(kx, hh);
        }
        __syncthreads();

        bf16x8 qfh[2][2], qfl[2][2];
        float mv[2], lv[2];
#pragma unroll
        for (int nt = 0; nt < 2; ++nt) {
            int t = t0 + w*32 + nt*16 + lm;
            const float* qrow = qh + ((size_t)bh*T_LEN + t)*HD;
#pragma unroll
            for (int f = 0; f < 2; ++f) {
                float4 x0 = *(const float4*)(qrow + f*32 + lq*8);
                float4 x1 = *(const float4*)(qrow + f*32 + lq*8 + 4);
                bf16x8 h8, l8;
                h8[0]=(short)f2bf(x0.x); h8[1]=(short)f2bf(x0.y);
                h8[2]=(short)f2bf(x0.z); h8[3]=(short)f2bf(x0.w);
                h8[4]=(short)f2bf(x1.x); h8[5]=(short)f2bf(x1.y);
                h8[6]=(short)f2bf(x1.z); h8[7]=(short)f2bf(x1.w);
                l8[0]=(short)f2bf(x0.x-bf2f((unsigned short)h8[0]));
                l8[1]=(short)f2bf(x0.y-bf2f((unsigned short)h8[1]));
                l8[2]=(short)f2bf(x0.z-bf2f((unsigned short)h8[2]));
                l8[3]=(short)f2bf(x0.w-bf2f((unsigned short)h8[3]));
                l8[4]=(short)f2bf(x1.x-bf2f((unsigned short)h8[4]));
                l8[5]=(short)f2bf(x1.y-bf2f((unsigned short)h8[5]));
                l8[6]=(short)f2bf(x1.z-bf2f((unsigned short)h8[6]));
                l8[7]=(short)f2bf(x1.w-bf2f((unsigned short)h8[7]));
                qfh[nt][f] = h8; qfl[nt][f] = l8;
            }
            mv[nt] = mbuf[(size_t)bh*T_LEN + t];
            lv[nt] = 1.0f / lbuf[(size_t)bh*T_LEN + t];
        }
#pragma unroll
        for (int ms = 0; ms < 8; ++ms) {
            const int krow = ms*16 + lm;
            bf16x8 ah0 = *(const bf16x8*)&Khi[krow][lq*8];
            bf16x8 ah1 = *(const bf16x8*)&Khi[krow][lq*8+32];
            bf16x8 al0 = *(const bf16x8*)&Klo[krow][lq*8];
            bf16x8 al1 = *(const bf16x8*)&Klo[krow][lq*8+32];
#pragma unroll
            for (int nt = 0; nt < 2; ++nt) {
                f32x4 s4 = {0.f,0.f,0.f,0.f};
                s4 = MFMA32(al0, qfh[nt][0], s4);
                s4 = MFMA32(al1, qfh[nt][1], s4);
                s4 = MFMA32(ah0, qfl[nt][0], s4);
                s4 = MFMA32(ah1, qfl[nt][1], s4);
                s4 = MFMA32(ah0, qfh[nt][0], s4);
                s4 = MFMA32(ah1, qfh[nt][1], s4);
                f32x4 a = acc[nt][ms];
                a[0] += __expf(s4[0]-mv[nt])*lv[nt];
                a[1] += __expf(s4[1]-mv[nt])*lv[nt];
                a[2] += __expf(s4[2]-mv[nt])*lv[nt];
                a[3] += __expf(s4[3]-mv[nt])*lv[nt];
                acc[nt][ms] = a;
            }
        }
    }
    const float sc = 1.0f / HEADS;
#pragma unroll
    for (int nt = 0; nt < 2; ++nt) {
        int t = t0 + w*32 + nt*16 + lm;
#pragma unroll
        for (int ms = 0; ms < 8; ++ms) {
            float4 v;
            v.x = acc[nt][ms][0]*sc; v.y = acc[nt][ms][1]*sc;
            v.z = acc[nt][ms][2]*sc; v.w = acc[nt][ms][3]*sc;
            *(float4*)(avg + ((size_t)b*T_LEN + t)*T_LEN + s0 + ms*16 + lq*4) = v;
        }
    }
}

extern "C" void kernel_launch(void* const* d_in, const int* in_sizes, int n_in,
                              void* d_out, int out_size, void* d_ws, size_t ws_size,
                              hipStream_t stream)
{
    const float* query = (const float*)d_in[0];
    const float* key   = (const float*)d_in[1];
    const float* value = (const float*)d_in[2];
    const float* Wq = (const float*)d_in[3];
    const float* bq = (const float*)d_in[4];
    const float* Wk = (const float*)d_in[5];
    const float* bk = (const float*)d_in[6];
    const float* Wv = (const float*)d_in[7];
    const float* bv = (const float*)d_in[8];
    const float* Wo = (const float*)d_in[9];
    const float* bo = (const float*)d_in[10];

    float* out = (float*)d_out;                  // [T,B,E]
    float* avg = out + (size_t)R_ROWS*EMB;       // [B,T,S]

    float* ws   = (float*)d_ws;
    float* qhw  = ws;                                    // [BH][T][HD]
    float* khw  = qhw + (size_t)BH*T_LEN*HD;             // [BH][T][HD]
    float* vtw  = khw + (size_t)BH*T_LEN*HD;             // [BH][HD][T] (transposed)
    float* mb   = vtw + (size_t)BH*T_LEN*HD;             // [BH][T]
    float* lb   = mb  + (size_t)BH*T_LEN;
    float* attn = lb  + (size_t)BH*T_LEN;                // [T,B,E]

    const float scale = 0.125f;  // HEAD_DIM^-0.5

    dim3 gGemm(R_ROWS/64, EMB/64);
    proj_kernel<<<gGemm, 256, 0, stream>>>(query, Wq, bq, qhw, scale, 1);
    proj_kernel<<<gGemm, 256, 0, stream>>>(key,   Wk, bk, khw, 1.0f,  1);
    proj_kernel<<<gGemm, 256, 0, stream>>>(value, Wv, bv, vtw, 1.0f,  2);
    flash_kernel<<<dim3(T_LEN/128, BH), 256, 0, stream>>>(qhw, khw, vtw, attn, mb, lb);
    proj_kernel<<<gGemm, 256, 0, stream>>>(attn, Wo, bo, out, 1.0f, 0);
    avg_kernel<<<dim3(T_LEN/128, T_LEN/128, B_SZ), 256, 0, stream>>>(qhw, khw, mb, lb, avg);
}

// Round 3
// 434.726 us; speedup vs baseline: 5.3189x; 2.4899x over previous
//
#include <hip/hip_runtime.h>
#include <math.h>

#define T_LEN 2048
#define B_SZ 2
#define EMB 1024
#define HEADS 16
#define HD 64
#define BH (B_SZ*HEADS)       // 32
#define R_ROWS (T_LEN*B_SZ)   // 4096

typedef unsigned short u16;
typedef __attribute__((ext_vector_type(8))) short bf16x8;
typedef __attribute__((ext_vector_type(4))) short bf16x4;
typedef __attribute__((ext_vector_type(4))) float f32x4;

#define MFMA32(a,b,c) __builtin_amdgcn_mfma_f32_16x16x32_bf16(a,b,c,0,0,0)
#if __has_builtin(__builtin_amdgcn_mfma_f32_16x16x16_bf16)
#define MFMA16(a,b,c) __builtin_amdgcn_mfma_f32_16x16x16_bf16(a,b,c,0,0,0)
#else
#define MFMA16(a,b,c) __builtin_amdgcn_mfma_f32_16x16x16bf16_1k(a,b,c,0,0,0)
#endif

__device__ __forceinline__ u16 f2bf(float f) {
    union { float f; unsigned int u; } v; v.f = f;
    unsigned int r = v.u + 0x7fffu + ((v.u >> 16) & 1u);
    return (u16)(r >> 16);
}
__device__ __forceinline__ float bf2f(u16 h) {
    union { unsigned int u; float f; } v; v.u = ((unsigned int)h) << 16;
    return v.f;
}
__device__ __forceinline__ ushort4 hi4(float4 x) {
    ushort4 u; u.x = f2bf(x.x); u.y = f2bf(x.y); u.z = f2bf(x.z); u.w = f2bf(x.w); return u;
}
__device__ __forceinline__ ushort4 lo4(float4 x, ushort4 h) {
    ushort4 u;
    u.x = f2bf(x.x - bf2f(h.x));
    u.y = f2bf(x.y - bf2f(h.y));
    u.z = f2bf(x.z - bf2f(h.z));
    u.w = f2bf(x.w - bf2f(h.w));
    return u;
}
// async global->LDS, 16B/lane; lds base must be wave-uniform (lane lands at base + lane*16)
__device__ __forceinline__ void lds_cp16(u16* lds, const u16* g) {
    __builtin_amdgcn_global_load_lds(
        (const __attribute__((address_space(1))) unsigned int*)(const void*)g,
        (__attribute__((address_space(3))) unsigned int*)(void*)lds,
        16, 0, 0);
}

// ---------------- fp32 -> bf16 hi/lo split (grid-stride-free exact grid) ----
__global__ __launch_bounds__(256)
void conv_kernel(const float* __restrict__ src, u16* __restrict__ hi, u16* __restrict__ lo)
{
    size_t base = ((size_t)blockIdx.x*256 + threadIdx.x)*8;
    float4 a = *(const float4*)(src + base);
    float4 b = *(const float4*)(src + base + 4);
    ushort4 h0 = hi4(a), h1 = hi4(b);
    ushort4 l0 = lo4(a, h0), l1 = lo4(b, h1);
    *(ushort4*)(hi + base)     = h0;
    *(ushort4*)(hi + base + 4) = h1;
    *(ushort4*)(lo + base)     = l0;
    *(ushort4*)(lo + base + 4) = l1;
}

// ---------------- MFMA projection GEMM (compensated bf16) --------------------
// C = A·B^T + bias, both A,B stored [rows][K=1024] bf16 hi/lo. 128(M)x64(N) tile,
// BK=32, 256 thr. XOR chunk swizzle: LDS physical 16B-chunk c holds logical
// chunk c ^ ((row>>1)&3)  -> frag ds_read_b128 is 2-way bank aliased (free).
// mode 0: outF[r][n] fp32 (O-proj). mode 1: q/k head-major hi/lo bf16, *scale.
// mode 2: A=W (m=out channel), B=X (n=token row) -> vT bf16 [bh][d][t].
__global__ __launch_bounds__(256)
void proj_mfma(const u16* __restrict__ Ahi, const u16* __restrict__ Alo,
               const u16* __restrict__ Bhi, const u16* __restrict__ Blo,
               const float* __restrict__ bias,
               float* __restrict__ outF, u16* __restrict__ outHi, u16* __restrict__ outLo,
               float scale, int mode)
{
    __shared__ __align__(16) u16 sAh[128*32];
    __shared__ __align__(16) u16 sAl[128*32];
    __shared__ __align__(16) u16 sBh[64*32];
    __shared__ __align__(16) u16 sBl[64*32];
    const int tid = threadIdx.x;
    const int w = tid >> 6, ln = tid & 63, lm = ln & 15, lq = ln >> 4;
    const int wm = w & 1, wn = w >> 1;
    const int m0 = blockIdx.x * 128, n0 = blockIdx.y * 64;
    const int K = 1024;
    const int ar = ln >> 2;      // staging: row within 16-row chunk
    const int ac = ln & 3;       // staging: 16B chunk within 64B row

    f32x4 acc[4][2];
#pragma unroll
    for (int i = 0; i < 4; ++i)
#pragma unroll
        for (int j = 0; j < 2; ++j) acc[i][j] = (f32x4){0.f,0.f,0.f,0.f};

    for (int k0 = 0; k0 < 1024; k0 += 32) {
#pragma unroll
        for (int i = 0; i < 2; ++i) {
            int ch = w*2 + i;
            int r = ch*16 + ar;
            int c = ac ^ ((r >> 1) & 3);
            size_t g = (size_t)(m0 + r)*K + k0 + c*8;
            lds_cp16(&sAh[ch*512], Ahi + g);
            lds_cp16(&sAl[ch*512], Alo + g);
        }
        {
            int r = w*16 + ar;
            int c = ac ^ ((r >> 1) & 3);
            size_t g = (size_t)(n0 + r)*K + k0 + c*8;
            lds_cp16(&sBh[w*512], Bhi + g);
            lds_cp16(&sBl[w*512], Blo + g);
        }
        __syncthreads();
        bf16x8 afh[4], afl[4], bfh[2], bfl[2];
#pragma unroll
        for (int i = 0; i < 4; ++i) {
            int row = wm*64 + i*16 + lm;
            int off = row*32 + (lq ^ ((row >> 1) & 3))*8;
            afh[i] = *(const bf16x8*)&sAh[off];
            afl[i] = *(const bf16x8*)&sAl[off];
        }
#pragma unroll
        for (int j = 0; j < 2; ++j) {
            int row = wn*32 + j*16 + lm;
            int off = row*32 + (lq ^ ((row >> 1) & 3))*8;
            bfh[j] = *(const bf16x8*)&sBh[off];
            bfl[j] = *(const bf16x8*)&sBl[off];
        }
#pragma unroll
        for (int i = 0; i < 4; ++i)
#pragma unroll
            for (int j = 0; j < 2; ++j) {
                f32x4 a = acc[i][j];
                a = MFMA32(afh[i], bfl[j], a);
                a = MFMA32(afl[i], bfh[j], a);
                a = MFMA32(afh[i], bfh[j], a);
                acc[i][j] = a;
            }
        __syncthreads();
    }

    if (mode == 0) {
#pragma unroll
        for (int j = 0; j < 2; ++j) {
            float bv = bias[n0 + wn*32 + j*16 + lm];
#pragma unroll
            for (int i = 0; i < 4; ++i)
#pragma unroll
                for (int r = 0; r < 4; ++r) {
                    int gm = m0 + wm*64 + i*16 + lq*4 + r;
                    outF[(size_t)gm*EMB + n0 + wn*32 + j*16 + lm] = acc[i][j][r] + bv;
                }
        }
    } else if (mode == 1) {
        const int h = n0 >> 6;
#pragma unroll
        for (int j = 0; j < 2; ++j) {
            float bv = bias[n0 + wn*32 + j*16 + lm];
            int d = wn*32 + j*16 + lm;
#pragma unroll
            for (int i = 0; i < 4; ++i)
#pragma unroll
                for (int r = 0; r < 4; ++r) {
                    int gm = m0 + wm*64 + i*16 + lq*4 + r;
                    int t = gm >> 1, bb = gm & 1;
                    float val = (acc[i][j][r] + bv) * scale;
                    u16 hv = f2bf(val);
                    u16 lv = f2bf(val - bf2f(hv));
                    size_t o = ((size_t)(bb*HEADS + h)*T_LEN + t)*HD + d;
                    outHi[o] = hv; outLo[o] = lv;
                }
        }
    } else {
#pragma unroll
        for (int i = 0; i < 4; ++i)
#pragma unroll
            for (int r = 0; r < 4; ++r) {
                int gm = m0 + wm*64 + i*16 + lq*4 + r;   // W row = out channel
                int h = gm >> 6, d = gm & 63;
                float bv = bias[gm];
#pragma unroll
                for (int j = 0; j < 2; ++j) {
                    int gn = n0 + wn*32 + j*16 + lm;     // X row = token
                    int t = gn >> 1, bb = gn & 1;
                    outHi[((size_t)(bb*HEADS + h)*HD + d)*T_LEN + t] = f2bf(acc[i][j][r] + bv);
                }
            }
    }
}

// ---------------- MFMA flash attention (bf16 hi/lo inputs) -------------------
// S^T = K·Q^T so the score C-frag is directly the PV A-frag. 128 t per block.
// K/V staged via global_load_lds with XOR-8 chunk swizzle (2-way = free).
__global__ __launch_bounds__(256)
void flash_kernel(const u16* __restrict__ qHi, const u16* __restrict__ qLo,
                  const u16* __restrict__ kHi, const u16* __restrict__ kLo,
                  const u16* __restrict__ vT,
                  u16* __restrict__ attnHi, u16* __restrict__ attnLo,
                  float* __restrict__ mbuf, float* __restrict__ lbuf)
{
    __shared__ __align__(16) u16 Khi[64*64];
    __shared__ __align__(16) u16 Klo[64*64];
    __shared__ __align__(16) u16 Vts[64*64];   // logical [d][s]
    const int tid = threadIdx.x;
    const int w = tid >> 6, ln = tid & 63, lm = ln & 15, lq = ln >> 4;
    const int bh = blockIdx.y;
    const int t0 = blockIdx.x * 128;
    const int b = bh >> 4, hh = bh & 15;
    const int sr = ln >> 3, scc = ln & 7;      // staging decode (128B rows)

    bf16x8 qfhi[2][2], qflo[2][2];
#pragma unroll
    for (int nt = 0; nt < 2; ++nt) {
        size_t qo = ((size_t)bh*T_LEN + t0 + w*32 + nt*16 + lm)*HD;
#pragma unroll
        for (int f = 0; f < 2; ++f) {
            qfhi[nt][f] = *(const bf16x8*)(qHi + qo + f*32 + lq*8);
            qflo[nt][f] = *(const bf16x8*)(qLo + qo + f*32 + lq*8);
        }
    }

    f32x4 O[2][4];
    float m_t[2], l_t[2];
#pragma unroll
    for (int nt = 0; nt < 2; ++nt) {
        m_t[nt] = -INFINITY; l_t[nt] = 0.f;
#pragma unroll
        for (int dt = 0; dt < 4; ++dt) O[nt][dt] = (f32x4){0.f,0.f,0.f,0.f};
    }

    for (int s0 = 0; s0 < T_LEN; s0 += 64) {
        __syncthreads();
#pragma unroll
        for (int i = 0; i < 2; ++i) {
            int ch = w*2 + i;
            int r = ch*8 + sr;
            int c = scc ^ (r & 7);
            lds_cp16(&Khi[ch*512], kHi + ((size_t)bh*T_LEN + s0 + r)*HD + c*8);
            lds_cp16(&Klo[ch*512], kLo + ((size_t)bh*T_LEN + s0 + r)*HD + c*8);
            lds_cp16(&Vts[ch*512], vT  + ((size_t)bh*HD + r)*T_LEN + s0 + c*8);
        }
        __syncthreads();

        f32x4 S[2][4];
#pragma unroll
        for (int ms = 0; ms < 4; ++ms) {
            const int kr = ms*16 + lm;
            const int sw = kr & 7;
            const u16* rowH = &Khi[kr*64];
            const u16* rowL = &Klo[kr*64];
            bf16x8 ah0 = *(const bf16x8*)(rowH + ((lq    ) ^ sw)*8);
            bf16x8 ah1 = *(const bf16x8*)(rowH + ((lq + 4) ^ sw)*8);
            bf16x8 al0 = *(const bf16x8*)(rowL + ((lq    ) ^ sw)*8);
            bf16x8 al1 = *(const bf16x8*)(rowL + ((lq + 4) ^ sw)*8);
#pragma unroll
            for (int nt = 0; nt < 2; ++nt) {
                f32x4 s4 = {0.f,0.f,0.f,0.f};
                s4 = MFMA32(al0, qfhi[nt][0], s4);
                s4 = MFMA32(al1, qfhi[nt][1], s4);
                s4 = MFMA32(ah0, qflo[nt][0], s4);
                s4 = MFMA32(ah1, qflo[nt][1], s4);
                s4 = MFMA32(ah0, qfhi[nt][0], s4);
                s4 = MFMA32(ah1, qfhi[nt][1], s4);
                S[nt][ms] = s4;
            }
        }

        bf16x4 P[2][4];
        float alpha[2];
#pragma unroll
        for (int nt = 0; nt < 2; ++nt) {
            float mx = -INFINITY;
#pragma unroll
            for (int ms = 0; ms < 4; ++ms)
#pragma unroll
                for (int r = 0; r < 4; ++r) mx = fmaxf(mx, S[nt][ms][r]);
            mx = fmaxf(mx, __shfl_xor(mx, 16));
            mx = fmaxf(mx, __shfl_xor(mx, 32));
            float mn = fmaxf(m_t[nt], mx);
            alpha[nt] = __expf(m_t[nt] - mn);
            m_t[nt] = mn;
            float rs = 0.f;
#pragma unroll
            for (int ms = 0; ms < 4; ++ms) {
                float p0 = __expf(S[nt][ms][0]-mn);
                float p1 = __expf(S[nt][ms][1]-mn);
                float p2 = __expf(S[nt][ms][2]-mn);
                float p3 = __expf(S[nt][ms][3]-mn);
                rs += (p0+p1)+(p2+p3);
                bf16x4 pk;
                pk[0] = (short)f2bf(p0); pk[1] = (short)f2bf(p1);
                pk[2] = (short)f2bf(p2); pk[3] = (short)f2bf(p3);
                P[nt][ms] = pk;
            }
            rs += __shfl_xor(rs, 16);
            rs += __shfl_xor(rs, 32);
            l_t[nt] = l_t[nt]*alpha[nt] + rs;
        }
#pragma unroll
        for (int nt = 0; nt < 2; ++nt) {
            f32x4 av;
#pragma unroll
            for (int r = 0; r < 4; ++r) av[r] = __shfl(alpha[nt], lq*4 + r);
#pragma unroll
            for (int dt = 0; dt < 4; ++dt) O[nt][dt] *= av;
        }
#pragma unroll
        for (int dt = 0; dt < 4; ++dt) {
            const int d = dt*16 + lm;
            const int dw = d & 7;
#pragma unroll
            for (int ms = 0; ms < 4; ++ms) {
                bf16x4 vf = *(const bf16x4*)&Vts[d*64 + ((2*ms + (lq>>1)) ^ dw)*8 + (lq&1)*4];
#pragma unroll
                for (int nt = 0; nt < 2; ++nt)
                    O[nt][dt] = MFMA16(P[nt][ms], vf, O[nt][dt]);
            }
        }
    }

#pragma unroll
    for (int nt = 0; nt < 2; ++nt) {
        float inv = 1.0f / l_t[nt];
        f32x4 iv;
#pragma unroll
        for (int r = 0; r < 4; ++r) iv[r] = __shfl(inv, lq*4 + r);
        int tbase = t0 + w*32 + nt*16;
        if (lq == 0) {
            mbuf[(size_t)bh*T_LEN + tbase + lm] = m_t[nt];
            lbuf[(size_t)bh*T_LEN + tbase + lm] = l_t[nt];
        }
#pragma unroll
        for (int dt = 0; dt < 4; ++dt)
#pragma unroll
            for (int r = 0; r < 4; ++r) {
                int t = tbase + lq*4 + r;
                float val = O[nt][dt][r] * iv[r];
                u16 hv = f2bf(val);
                u16 lv = f2bf(val - bf2f(hv));
                size_t o = ((size_t)t*B_SZ + b)*EMB + hh*HD + dt*16 + lm;
                attnHi[o] = hv; attnLo[o] = lv;
            }
    }
}

// ---------------- avg weights: MFMA recompute S^T, apply saved (m,l) ---------
__global__ __launch_bounds__(256)
void avg_kernel(const u16* __restrict__ qHi, const u16* __restrict__ qLo,
                const u16* __restrict__ kHi, const u16* __restrict__ kLo,
                const float* __restrict__ mbuf, const float* __restrict__ lbuf,
                float* __restrict__ avg)
{
    __shared__ __align__(16) u16 Khi[128*64];
    __shared__ __align__(16) u16 Klo[128*64];
    const int tid = threadIdx.x;
    const int w = tid >> 6, ln = tid & 63, lm = ln & 15, lq = ln >> 4;
    const int s0 = blockIdx.x * 128;
    const int t0 = blockIdx.y * 128;
    const int b  = blockIdx.z;
    const int sr = ln >> 3, scc = ln & 7;
    f32x4 acc[2][8];
#pragma unroll
    for (int nt = 0; nt < 2; ++nt)
#pragma unroll
        for (int ms = 0; ms < 8; ++ms) acc[nt][ms] = (f32x4){0.f,0.f,0.f,0.f};

    for (int h = 0; h < HEADS; ++h) {
        const int bh = b*HEADS + h;
        __syncthreads();
#pragma unroll
        for (int i = 0; i < 4; ++i) {
            int ch = w*4 + i;
            int r = ch*8 + sr;
            int c = scc ^ (r & 7);
            size_t g = ((size_t)bh*T_LEN + s0 + r)*HD + c*8;
            lds_cp16(&Khi[ch*512], kHi + g);
            lds_cp16(&Klo[ch*512], kLo + g);
        }
        __syncthreads();

        bf16x8 qfh[2][2], qfl[2][2];
        float mv[2], lv[2];
#pragma unroll
        for (int nt = 0; nt < 2; ++nt) {
            int t = t0 + w*32 + nt*16 + lm;
            size_t qo = ((size_t)bh*T_LEN + t)*HD;
#pragma unroll
            for (int f = 0; f < 2; ++f) {
                qfh[nt][f] = *(const bf16x8*)(qHi + qo + f*32 + lq*8);
                qfl[nt][f] = *(const bf16x8*)(qLo + qo + f*32 + lq*8);
            }
            mv[nt] = mbuf[(size_t)bh*T_LEN + t];
            lv[nt] = 1.0f / lbuf[(size_t)bh*T_LEN + t];
        }
#pragma unroll
        for (int ms = 0; ms < 8; ++ms) {
            const int kr = ms*16 + lm;
            const int sw = kr & 7;
            const u16* rowH = &Khi[kr*64];
            const u16* rowL = &Klo[kr*64];
            bf16x8 ah0 = *(const bf16x8*)(rowH + ((lq    ) ^ sw)*8);
            bf16x8 ah1 = *(const bf16x8*)(rowH + ((lq + 4) ^ sw)*8);
            bf16x8 al0 = *(const bf16x8*)(rowL + ((lq    ) ^ sw)*8);
            bf16x8 al1 = *(const bf16x8*)(rowL + ((lq + 4) ^ sw)*8);
#pragma unroll
            for (int nt = 0; nt < 2; ++nt) {
                f32x4 s4 = {0.f,0.f,0.f,0.f};
                s4 = MFMA32(al0, qfh[nt][0], s4);
                s4 = MFMA32(al1, qfh[nt][1], s4);
                s4 = MFMA32(ah0, qfl[nt][0], s4);
                s4 = MFMA32(ah1, qfl[nt][1], s4);
                s4 = MFMA32(ah0, qfh[nt][0], s4);
                s4 = MFMA32(ah1, qfh[nt][1], s4);
                f32x4 a = acc[nt][ms];
                a[0] += __expf(s4[0]-mv[nt])*lv[nt];
                a[1] += __expf(s4[1]-mv[nt])*lv[nt];
                a[2] += __expf(s4[2]-mv[nt])*lv[nt];
                a[3] += __expf(s4[3]-mv[nt])*lv[nt];
                acc[nt][ms] = a;
            }
        }
    }
    const float sc = 1.0f / HEADS;
#pragma unroll
    for (int nt = 0; nt < 2; ++nt) {
        int t = t0 + w*32 + nt*16 + lm;
#pragma unroll
        for (int ms = 0; ms < 8; ++ms) {
            float4 v;
            v.x = acc[nt][ms][0]*sc; v.y = acc[nt][ms][1]*sc;
            v.z = acc[nt][ms][2]*sc; v.w = acc[nt][ms][3]*sc;
            *(float4*)(avg + ((size_t)b*T_LEN + t)*T_LEN + s0 + ms*16 + lq*4) = v;
        }
    }
}

extern "C" void kernel_launch(void* const* d_in, const int* in_sizes, int n_in,
                              void* d_out, int out_size, void* d_ws, size_t ws_size,
                              hipStream_t stream)
{
    const float* query = (const float*)d_in[0];
    const float* key   = (const float*)d_in[1];
    const float* value = (const float*)d_in[2];
    const float* Wq = (const float*)d_in[3];
    const float* bq = (const float*)d_in[4];
    const float* Wk = (const float*)d_in[5];
    const float* bk = (const float*)d_in[6];
    const float* Wv = (const float*)d_in[7];
    const float* bv = (const float*)d_in[8];
    const float* Wo = (const float*)d_in[9];
    const float* bo = (const float*)d_in[10];

    float* out = (float*)d_out;                  // [T,B,E]
    float* avg = out + (size_t)R_ROWS*EMB;       // [B,T,S]

    const size_t NX = (size_t)R_ROWS*EMB;        // 4194304
    const size_t NW = (size_t)EMB*EMB;           // 1048576
    u16* wsu = (u16*)d_ws;
    u16* cHi  = wsu;            u16* cLo  = cHi + NX;     // conv scratch; later attnHi/Lo
    u16* WqHi = cLo + NX;       u16* WqLo = WqHi + NW;
    u16* WkHi = WqLo + NW;      u16* WkLo = WkHi + NW;
    u16* WvHi = WkLo + NW;      u16* WvLo = WvHi + NW;
    u16* WoHi = WvLo + NW;      u16* WoLo = WoHi + NW;
    u16* qHi  = WoLo + NW;      u16* qLo  = qHi + NX;     // head-major [bh][t][d]
    u16* kHi  = qLo + NX;       u16* kLo  = kHi + NX;
    u16* vT   = kLo + NX;                                  // [bh][d][t]
    float* mb = (float*)(vT + NX);
    float* lb = mb + (size_t)BH*T_LEN;

    const float scale = 0.125f;  // HEAD_DIM^-0.5

    // weight hi/lo splits
    conv_kernel<<<NW/2048, 256, 0, stream>>>(Wq, WqHi, WqLo);
    conv_kernel<<<NW/2048, 256, 0, stream>>>(Wk, WkHi, WkLo);
    conv_kernel<<<NW/2048, 256, 0, stream>>>(Wv, WvHi, WvLo);
    conv_kernel<<<NW/2048, 256, 0, stream>>>(Wo, WoHi, WoLo);

    dim3 gP(R_ROWS/128, EMB/64);       // (32,16) modes 0/1
    dim3 gPv(EMB/128, R_ROWS/64);      // (8,64)  mode 2

    conv_kernel<<<NX/2048, 256, 0, stream>>>(query, cHi, cLo);
    proj_mfma<<<gP, 256, 0, stream>>>(cHi, cLo, WqHi, WqLo, bq, nullptr, qHi, qLo, scale, 1);
    conv_kernel<<<NX/2048, 256, 0, stream>>>(key, cHi, cLo);
    proj_mfma<<<gP, 256, 0, stream>>>(cHi, cLo, WkHi, WkLo, bk, nullptr, kHi, kLo, 1.0f, 1);
    conv_kernel<<<NX/2048, 256, 0, stream>>>(value, cHi, cLo);
    proj_mfma<<<gPv, 256, 0, stream>>>(WvHi, WvLo, cHi, cLo, bv, nullptr, vT, nullptr, 1.0f, 2);

    flash_kernel<<<dim3(T_LEN/128, BH), 256, 0, stream>>>(qHi, qLo, kHi, kLo, vT,
                                                          cHi, cLo, mb, lb);
    proj_mfma<<<gP, 256, 0, stream>>>(cHi, cLo, WoHi, WoLo, bo, out, nullptr, nullptr, 1.0f, 0);
    avg_kernel<<<dim3(T_LEN/128, T_LEN/128, B_SZ), 256, 0, stream>>>(qHi, qLo, kHi, kLo, mb, lb, avg);
}